// Round 1
// baseline (541.846 us; speedup 1.0000x reference)
//
#include <hip/hip_runtime.h>

typedef _Float16 half8 __attribute__((ext_vector_type(8)));
typedef _Float16 h4 __attribute__((ext_vector_type(4)));
typedef float floatx4 __attribute__((ext_vector_type(4)));

#define NTOK 16384
#define DM   4096
#define NE   128
#define MT   64      // tokens per block
#define BK   64      // k-chunk
#define TEMP 0.3f

// ---------------- prep: split wg fp32 -> f16 hi + f16 residual*2048 ----------------
__global__ void split_b_kernel(const float* __restrict__ wg,
                               _Float16* __restrict__ b1, _Float16* __restrict__ b2) {
    int i = blockIdx.x * blockDim.x + threadIdx.x;          // one float4 per thread
    float4 v = ((const float4*)wg)[i];
    h4 h1, h2;
    h1[0] = (_Float16)v.x; h1[1] = (_Float16)v.y; h1[2] = (_Float16)v.z; h1[3] = (_Float16)v.w;
    h2[0] = (_Float16)((v.x - (float)h1[0]) * 2048.0f);
    h2[1] = (_Float16)((v.y - (float)h1[1]) * 2048.0f);
    h2[2] = (_Float16)((v.z - (float)h1[2]) * 2048.0f);
    h2[3] = (_Float16)((v.w - (float)h1[3]) * 2048.0f);
    ((h4*)b1)[i] = h1;
    ((h4*)b2)[i] = h2;
}

// ---------------- main fused kernel: GEMM (f16x2 split) + topk + softmax + me/ce ----------------
__launch_bounds__(256, 2)
__global__ void moe_gate_kernel(const float* __restrict__ A,
                                const _Float16* __restrict__ B1,
                                const _Float16* __restrict__ B2,
                                float* __restrict__ out,
                                float* __restrict__ me_g,
                                float* __restrict__ ce_g) {
    __shared__ __align__(16) unsigned char smem[49152];
    _Float16* A1s = (_Float16*)smem;            // [64][64]  8KB
    _Float16* A2s = A1s + MT * BK;              // [64][64]  8KB
    _Float16* B1s = A2s + MT * BK;              // [128][64] 16KB
    _Float16* B2s = B1s + NE * BK;              // [128][64] 16KB

    const int tid  = threadIdx.x;
    const int wave = tid >> 6;
    const int lane = tid & 63;
    const int quad = lane >> 4;
    const int lrow = lane & 15;
    const int tok0 = blockIdx.x * MT;

    floatx4 accm[4][2], accc[4][2];
#pragma unroll
    for (int r = 0; r < 4; r++)
#pragma unroll
        for (int c = 0; c < 2; c++) {
            accm[r][c] = (floatx4){0.f, 0.f, 0.f, 0.f};
            accc[r][c] = (floatx4){0.f, 0.f, 0.f, 0.f};
        }

    // B-staging assignment: wave 0/1 -> B1 rows [0,64)/[64,128); wave 2/3 -> B2
    const _Float16* Bsrc = (wave < 2) ? B1 : B2;
    _Float16* Bdst = (wave < 2) ? B1s : B2s;
    const int rbase = (wave & 1) * 64;
    const int brow_off = lane >> 3;           // 0..7
    const int bcol     = (lane & 7) * 8;      // halfs

    // A-staging assignment (all 256 threads)
    const int arow  = tid >> 4;               // 0..15
    const int acol4 = (tid & 15) * 4;         // floats

    for (int k0 = 0; k0 < DM; k0 += BK) {
        // async B chunk -> LDS (8 instrs x 8 rows x 128B, lane scatter = lane*16B)
#pragma unroll
        for (int i = 0; i < 8; i++) {
            const _Float16* g = Bsrc + (size_t)(rbase + i * 8 + brow_off) * DM + k0 + bcol;
            _Float16* l = Bdst + (rbase + i * 8) * BK;     // wave-uniform base
            __builtin_amdgcn_global_load_lds(
                (const __attribute__((address_space(1))) unsigned int*)g,
                (__attribute__((address_space(3))) unsigned int*)l, 16, 0, 0);
        }
        // A chunk fp32 -> split f16 -> LDS
#pragma unroll
        for (int rr = 0; rr < 4; rr++) {
            int r = arow + rr * 16;
            float4 v = *(const float4*)(A + (size_t)(tok0 + r) * DM + k0 + acol4);
            h4 h1, h2;
            h1[0] = (_Float16)v.x; h1[1] = (_Float16)v.y; h1[2] = (_Float16)v.z; h1[3] = (_Float16)v.w;
            h2[0] = (_Float16)((v.x - (float)h1[0]) * 2048.0f);
            h2[1] = (_Float16)((v.y - (float)h1[1]) * 2048.0f);
            h2[2] = (_Float16)((v.z - (float)h1[2]) * 2048.0f);
            h2[3] = (_Float16)((v.w - (float)h1[3]) * 2048.0f);
            *(h4*)(A1s + r * BK + acol4) = h1;
            *(h4*)(A2s + r * BK + acol4) = h2;
        }
        __syncthreads();

#pragma unroll
        for (int ks = 0; ks < 2; ks++) {
            const int koff = ks * 32 + quad * 8;
            half8 a1[4], a2[4], b1f[2], b2f[2];
#pragma unroll
            for (int c = 0; c < 2; c++) {
                int e = wave * 32 + c * 16 + lrow;
                b1f[c] = *(half8*)(B1s + e * BK + koff);
                b2f[c] = *(half8*)(B2s + e * BK + koff);
            }
#pragma unroll
            for (int r = 0; r < 4; r++) {
                a1[r] = *(half8*)(A1s + (r * 16 + lrow) * BK + koff);
                a2[r] = *(half8*)(A2s + (r * 16 + lrow) * BK + koff);
            }
#pragma unroll
            for (int r = 0; r < 4; r++)
#pragma unroll
                for (int c = 0; c < 2; c++) {
                    accm[r][c] = __builtin_amdgcn_mfma_f32_16x16x32_f16(a1[r], b1f[c], accm[r][c], 0, 0, 0);
                    accc[r][c] = __builtin_amdgcn_mfma_f32_16x16x32_f16(a1[r], b2f[c], accc[r][c], 0, 0, 0);
                    accc[r][c] = __builtin_amdgcn_mfma_f32_16x16x32_f16(a2[r], b1f[c], accc[r][c], 0, 0, 0);
                }
        }
        __syncthreads();
    }

    // ---------------- epilogue (reuse smem) ----------------
    float* LG     = (float*)smem;          // [128][66] logits, expert-major, pad +2
    float* tmax   = LG + NE * 66;          // [64]
    float* tscale = tmax + MT;             // [64]
    int*   hist   = (int*)(tscale + MT);   // [128]

#pragma unroll
    for (int r = 0; r < 4; r++)
#pragma unroll
        for (int c = 0; c < 2; c++) {
            int e = wave * 32 + c * 16 + lrow;
#pragma unroll
            for (int g = 0; g < 4; g++) {
                int t = r * 16 + quad * 4 + g;
                LG[e * 66 + t] = accm[r][c][g] + accc[r][c][g] * (1.0f / 2048.0f);
            }
        }
    if (tid < NE) hist[tid] = 0;
    __syncthreads();

    if (tid < MT) {
        const int t = tid;
        float m1 = -1e30f, m2 = -1e30f;
        int i1 = 0, i2 = 0;
        for (int e = 0; e < NE; e++) {
            float v = LG[e * 66 + t];
            if (v > m1) { m2 = m1; i2 = i1; m1 = v; i1 = e; }
            else if (v > m2) { m2 = v; i2 = e; }
        }
        float s = 0.f;
        for (int e = 0; e < NE; e++)
            s += __expf((LG[e * 66 + t] - m1) * (1.0f / TEMP));
        tmax[t] = m1;
        tscale[t] = 1.0f / s;
        atomicAdd(&hist[i1], 1);

        const int tg = tok0 + t;
        out[tg * 2 + 0] = (float)i1;
        out[tg * 2 + 1] = (float)i2;
        float d = __expf(m2 - m1);          // e^{v2-v1} <= 1
        float g1 = 1.0f / (1.0f + d);
        out[2 * NTOK + tg * 2 + 0] = g1;
        out[2 * NTOK + tg * 2 + 1] = d * g1;
    }
    __syncthreads();

    if (tid < NE) {
        const int e = tid;
        float s = 0.f;
        for (int t = 0; t < MT; t++)
            s += __expf((LG[e * 66 + t] - tmax[t]) * (1.0f / TEMP)) * tscale[t];
        atomicAdd(&me_g[e], s);
        atomicAdd(&ce_g[e], (float)hist[e] * ((float)NE / (float)NTOK));
    }
}

// ---------------- final: loss = sum(me*ce)/T ----------------
__global__ void loss_kernel(const float* __restrict__ me, const float* __restrict__ ce,
                            float* __restrict__ out) {
    int l = threadIdx.x;  // 64
    float v = me[l] * ce[l] + me[l + 64] * ce[l + 64];
#pragma unroll
    for (int off = 32; off; off >>= 1) v += __shfl_down(v, off);
    if (l == 0) out[4 * NTOK] = v / (float)NTOK;
}

extern "C" void kernel_launch(void* const* d_in, const int* in_sizes, int n_in,
                              void* d_out, int out_size, void* d_ws, size_t ws_size,
                              hipStream_t stream) {
    (void)in_sizes; (void)n_in; (void)out_size; (void)ws_size;
    const float* inp = (const float*)d_in[0];
    const float* wg  = (const float*)d_in[1];
    float* out = (float*)d_out;

    _Float16* B1 = (_Float16*)d_ws;                         // 1 MB
    _Float16* B2 = B1 + (size_t)NE * DM;                    // 1 MB
    float* me = (float*)((char*)d_ws + 2u * 1024u * 1024u); // 512 B
    float* ce = me + NE;

    hipMemsetAsync(me, 0, 2 * NE * sizeof(float), stream);
    split_b_kernel<<<(NE * DM / 4) / 256, 256, 0, stream>>>(wg, B1, B2);
    moe_gate_kernel<<<NTOK / MT, 256, 0, stream>>>(inp, B1, B2, out, me, ce);
    loss_kernel<<<1, 64, 0, stream>>>(me, ce, out);
}

// Round 2
// 463.533 us; speedup vs baseline: 1.1689x; 1.1689x over previous
//
#include <hip/hip_runtime.h>

typedef _Float16 half8 __attribute__((ext_vector_type(8)));
typedef float floatx4 __attribute__((ext_vector_type(4)));

#define NTOK 16384
#define DM   4096
#define NE   128
#define MT   32            // tokens per block
#define BK   64            // k per iter
#define NITER (DM / BK)    // 64
#define NBLK (NTOK / MT)   // 512
#define TEMP 0.3f
#define CSTRIDE 528        // bytes per k-chunk slab: 32 rows * 16B + 16B pad
#define ABUF (8 * CSTRIDE) // 4224 B (one split matrix, one k-iter)
#define BUFSZ (2 * ABUF)   // 8448 B (A1 + A2)

// ---------------- prep: pack wg into MFMA b-fragment order, f16x2 split ----------------
// Layout: tile tg = kchunk*8 + egroup (kchunk: 32 k's, egroup: 16 experts).
// Per tile 2048 B: [b1: 64 lanes x 16B][b2: 64 lanes x 16B].
// Lane l, half j holds wg[(egroup*16 + (l&15))*DM + kchunk*32 + (l>>4)*8 + j].
__global__ void pack_b_kernel(const float* __restrict__ wg, _Float16* __restrict__ Bp) {
    int gtid = blockIdx.x * blockDim.x + threadIdx.x;   // 65536 threads
    int l  = gtid & 63;
    int tg = gtid >> 6;                                  // 0..1023
    int g  = tg & 7;
    int kc = tg >> 3;
    const float* src = wg + (size_t)(g * 16 + (l & 15)) * DM + kc * 32 + (l >> 4) * 8;
    float4 v0 = *(const float4*)src;
    float4 v1 = *(const float4*)(src + 4);
    float f[8] = {v0.x, v0.y, v0.z, v0.w, v1.x, v1.y, v1.z, v1.w};
    half8 h1, h2;
#pragma unroll
    for (int j = 0; j < 8; j++) {
        h1[j] = (_Float16)f[j];
        h2[j] = (_Float16)((f[j] - (float)h1[j]) * 2048.0f);
    }
    char* dst = (char*)Bp + (size_t)tg * 2048 + l * 16;
    *(half8*)dst = h1;
    *(half8*)(dst + 1024) = h2;
}

// ---------------- main fused kernel ----------------
__device__ __forceinline__ void stage_write(unsigned char* base, unsigned off,
                                            float4 v0, float4 v1) {
    float f[8] = {v0.x, v0.y, v0.z, v0.w, v1.x, v1.y, v1.z, v1.w};
    half8 h1, h2;
#pragma unroll
    for (int j = 0; j < 8; j++) {
        h1[j] = (_Float16)f[j];
        h2[j] = (_Float16)((f[j] - (float)h1[j]) * 2048.0f);
    }
    *(half8*)(base + off) = h1;
    *(half8*)(base + ABUF + off) = h2;
}

__launch_bounds__(256, 2)
__global__ void moe_gate_kernel(const float* __restrict__ A,
                                const _Float16* __restrict__ Bp,
                                float* __restrict__ out,
                                float* __restrict__ me_part,
                                float* __restrict__ ce_part) {
    __shared__ __align__(16) unsigned char smem[17664];  // 2*BUFSZ=16896 main; 17664 epilogue
    const int tid  = threadIdx.x;
    const int wave = tid >> 6;
    const int lane = tid & 63;
    const int quad = lane >> 4;
    const int lrow = lane & 15;
    const int tok0 = blockIdx.x * MT;

    // staging: thread t handles row t>>3 (0..31), k-chunk t&7 (8 halfs)
    const int srow = tid >> 3;
    const int schunk = tid & 7;
    const float* aptr = A + (size_t)(tok0 + srow) * DM + schunk * 8;
    const unsigned swoff = schunk * CSTRIDE + srow * 16;

    // compute-side per-lane LDS read offset
    const unsigned aroff = quad * CSTRIDE + lrow * 16;

    // B fragment base for this wave (expert groups wave*2, wave*2+1)
    const char* bB = (const char*)Bp + (wave * 2) * 2048 + lane * 16;

    floatx4 accm[2][2], accc[2][2];
#pragma unroll
    for (int r = 0; r < 2; r++)
#pragma unroll
        for (int c = 0; c < 2; c++) {
            accm[r][c] = (floatx4){0.f, 0.f, 0.f, 0.f};
            accc[r][c] = (floatx4){0.f, 0.f, 0.f, 0.f};
        }

    // prologue: stage iter 0
    {
        float4 v0 = *(const float4*)aptr;
        float4 v1 = *(const float4*)(aptr + 4);
        stage_write(smem, swoff, v0, v1);
    }
    __syncthreads();

    for (int it = 0; it < NITER; ++it) {
        float4 n0, n1;
        if (it < NITER - 1) {
            const float* p = aptr + (it + 1) * BK;
            n0 = *(const float4*)p;
            n1 = *(const float4*)(p + 4);
        }
        unsigned char* cb = smem + (it & 1) * BUFSZ;
        const char* bit = bB + (size_t)it * 32768;

#pragma unroll
        for (int ks = 0; ks < 2; ++ks) {
            half8 b1f[2], b2f[2], a1[2], a2[2];
#pragma unroll
            for (int c = 0; c < 2; c++) {
                b1f[c] = *(const half8*)(bit + ks * 16384 + c * 2048);
                b2f[c] = *(const half8*)(bit + ks * 16384 + c * 2048 + 1024);
            }
#pragma unroll
            for (int r = 0; r < 2; r++) {
                a1[r] = *(const half8*)(cb + ks * 2112 + r * 256 + aroff);
                a2[r] = *(const half8*)(cb + ABUF + ks * 2112 + r * 256 + aroff);
            }
#pragma unroll
            for (int r = 0; r < 2; r++)
#pragma unroll
                for (int c = 0; c < 2; c++) {
                    accm[r][c] = __builtin_amdgcn_mfma_f32_16x16x32_f16(a1[r], b1f[c], accm[r][c], 0, 0, 0);
                    accc[r][c] = __builtin_amdgcn_mfma_f32_16x16x32_f16(a1[r], b2f[c], accc[r][c], 0, 0, 0);
                    accc[r][c] = __builtin_amdgcn_mfma_f32_16x16x32_f16(a2[r], b1f[c], accc[r][c], 0, 0, 0);
                }
        }
        if (it < NITER - 1)
            stage_write(smem + ((it + 1) & 1) * BUFSZ, swoff, n0, n1);
        __syncthreads();
    }

    // ---------------- epilogue ----------------
    float* LG     = (float*)smem;                   // [128][33] fp32, 16896 B
    float* tmax   = (float*)(smem + 16896);         // 32
    float* tscale = tmax + 32;                      // 32
    int*   hist   = (int*)(tscale + 32);            // 128

#pragma unroll
    for (int r = 0; r < 2; r++)
#pragma unroll
        for (int c = 0; c < 2; c++) {
            int e = wave * 32 + c * 16 + lrow;
#pragma unroll
            for (int g = 0; g < 4; g++) {
                int t = r * 16 + quad * 4 + g;
                LG[e * 33 + t] = accm[r][c][g] + accc[r][c][g] * (1.0f / 2048.0f);
            }
        }
    if (tid < NE) hist[tid] = 0;
    __syncthreads();

    if (tid < MT) {
        const int t = tid;
        float m1 = -1e30f, m2 = -1e30f;
        int i1 = 0, i2 = 0;
        for (int e = 0; e < NE; e++) {
            float v = LG[e * 33 + t];
            if (v > m1) { m2 = m1; i2 = i1; m1 = v; i1 = e; }
            else if (v > m2) { m2 = v; i2 = e; }
        }
        float s = 0.f;
        for (int e = 0; e < NE; e++)
            s += __expf((LG[e * 33 + t] - m1) * (1.0f / TEMP));
        tmax[t] = m1;
        tscale[t] = 1.0f / s;
        atomicAdd(&hist[i1], 1);

        const int tg = tok0 + t;
        out[tg * 2 + 0] = (float)i1;
        out[tg * 2 + 1] = (float)i2;
        float d = __expf(m2 - m1);
        float g1 = 1.0f / (1.0f + d);
        out[2 * NTOK + tg * 2 + 0] = g1;
        out[2 * NTOK + tg * 2 + 1] = d * g1;
    }
    __syncthreads();

    if (tid < NE) {
        const int e = tid;
        float s = 0.f;
        for (int t = 0; t < MT; t++)
            s += __expf((LG[e * 33 + t] - tmax[t]) * (1.0f / TEMP)) * tscale[t];
        me_part[blockIdx.x * NE + e] = s;
        ce_part[blockIdx.x * NE + e] = (float)hist[e];
    }
}

// ---------------- finalize: reduce partials, loss ----------------
__global__ void finalize_kernel(const float* __restrict__ mp, const float* __restrict__ cp,
                                float* __restrict__ out) {
    __shared__ float red[2 * 8 * 128];
    __shared__ float wsum[2];
    const int tid = threadIdx.x;        // 1024
    const int e = tid & 127, seg = tid >> 7;
    float sm = 0.f, sc = 0.f;
    for (int b = seg; b < NBLK; b += 8) {
        sm += mp[b * NE + e];
        sc += cp[b * NE + e];
    }
    red[seg * 128 + e] = sm;
    red[1024 + seg * 128 + e] = sc;
    __syncthreads();
    if (tid < 128) {
        float me = 0.f, ce = 0.f;
#pragma unroll
        for (int s = 0; s < 8; s++) {
            me += red[s * 128 + tid];
            ce += red[1024 + s * 128 + tid];
        }
        ce *= (float)NE / (float)NTOK;
        float v = me * ce;
#pragma unroll
        for (int off = 32; off; off >>= 1) v += __shfl_down(v, off);
        if ((tid & 63) == 0) wsum[tid >> 6] = v;
    }
    __syncthreads();
    if (tid == 0) out[4 * NTOK] = (wsum[0] + wsum[1]) / (float)NTOK;
}

extern "C" void kernel_launch(void* const* d_in, const int* in_sizes, int n_in,
                              void* d_out, int out_size, void* d_ws, size_t ws_size,
                              hipStream_t stream) {
    (void)in_sizes; (void)n_in; (void)out_size; (void)ws_size;
    const float* inp = (const float*)d_in[0];
    const float* wg  = (const float*)d_in[1];
    float* out = (float*)d_out;

    _Float16* Bp = (_Float16*)d_ws;                          // 2 MB packed B
    float* mp = (float*)((char*)d_ws + (2u << 20));          // 256 KB me partials
    float* cp = mp + NBLK * NE;                              // 256 KB ce partials

    pack_b_kernel<<<256, 256, 0, stream>>>(wg, Bp);
    moe_gate_kernel<<<NBLK, 256, 0, stream>>>(inp, Bp, out, mp, cp);
    finalize_kernel<<<1, 1024, 0, stream>>>(mp, cp, out);
}

// Round 3
// 426.769 us; speedup vs baseline: 1.2696x; 1.0861x over previous
//
#include <hip/hip_runtime.h>

typedef _Float16 half8 __attribute__((ext_vector_type(8)));
typedef float floatx4 __attribute__((ext_vector_type(4)));

#define NTOK 16384
#define DM   4096
#define NE   128
#define MT   32            // tokens per block
#define BK   64            // k per iter
#define KSPLIT 2
#define KHALF (DM / KSPLIT)       // 2048
#define NITER (KHALF / BK)        // 32
#define NBLK_MAIN (NTOK / MT * KSPLIT)  // 1024
#define ET   64                   // tokens per epilogue block
#define NBLK_EPI (NTOK / ET)      // 256
#define TEMP 0.3f
#define CSTRIDE 528
#define ABUF (8 * CSTRIDE)
#define BUFSZ (2 * ABUF)

// ---------------- prep: pack wg into MFMA b-fragment order, f16x2 split ----------------
__global__ void pack_b_kernel(const float* __restrict__ wg, _Float16* __restrict__ Bp) {
    int gtid = blockIdx.x * blockDim.x + threadIdx.x;
    int l  = gtid & 63;
    int tg = gtid >> 6;
    int g  = tg & 7;
    int kc = tg >> 3;
    const float* src = wg + (size_t)(g * 16 + (l & 15)) * DM + kc * 32 + (l >> 4) * 8;
    float4 v0 = *(const float4*)src;
    float4 v1 = *(const float4*)(src + 4);
    float f[8] = {v0.x, v0.y, v0.z, v0.w, v1.x, v1.y, v1.z, v1.w};
    half8 h1, h2;
#pragma unroll
    for (int j = 0; j < 8; j++) {
        h1[j] = (_Float16)f[j];
        h2[j] = (_Float16)((f[j] - (float)h1[j]) * 2048.0f);
    }
    char* dst = (char*)Bp + (size_t)tg * 2048 + l * 16;
    *(half8*)dst = h1;
    *(half8*)(dst + 1024) = h2;
}

// ---------------- main GEMM kernel (K-split) ----------------
__device__ __forceinline__ void stage_write(unsigned char* base, unsigned off,
                                            float4 v0, float4 v1) {
    float f[8] = {v0.x, v0.y, v0.z, v0.w, v1.x, v1.y, v1.z, v1.w};
    half8 h1, h2;
#pragma unroll
    for (int j = 0; j < 8; j++) {
        h1[j] = (_Float16)f[j];
        h2[j] = (_Float16)((f[j] - (float)h1[j]) * 2048.0f);
    }
    *(half8*)(base + off) = h1;
    *(half8*)(base + ABUF + off) = h2;
}

__launch_bounds__(256, 4)
__global__ void moe_gemm_kernel(const float* __restrict__ A,
                                const _Float16* __restrict__ Bp,
                                float* __restrict__ part) {
    __shared__ __align__(16) unsigned char smem[2 * BUFSZ];
    const int tid  = threadIdx.x;
    const int wave = tid >> 6;
    const int lane = tid & 63;
    const int quad = lane >> 4;
    const int lrow = lane & 15;
    const int half = blockIdx.x & 1;
    const int tok0 = (blockIdx.x >> 1) * MT;

    const int srow = tid >> 3;
    const int schunk = tid & 7;
    const float* aptr = A + (size_t)(tok0 + srow) * DM + half * KHALF + schunk * 8;
    const unsigned swoff = schunk * CSTRIDE + srow * 16;
    const unsigned aroff = quad * CSTRIDE + lrow * 16;

    const char* bB = (const char*)Bp + (size_t)half * (1u << 20) + (wave * 2) * 2048 + lane * 16;

    floatx4 accm[2][2], accc[2][2];
#pragma unroll
    for (int r = 0; r < 2; r++)
#pragma unroll
        for (int c = 0; c < 2; c++) {
            accm[r][c] = (floatx4){0.f, 0.f, 0.f, 0.f};
            accc[r][c] = (floatx4){0.f, 0.f, 0.f, 0.f};
        }

    {
        float4 v0 = *(const float4*)aptr;
        float4 v1 = *(const float4*)(aptr + 4);
        stage_write(smem, swoff, v0, v1);
    }
    __syncthreads();

    for (int it = 0; it < NITER; ++it) {
        float4 n0, n1;
        if (it < NITER - 1) {
            const float* p = aptr + (it + 1) * BK;
            n0 = *(const float4*)p;
            n1 = *(const float4*)(p + 4);
        }
        unsigned char* cb = smem + (it & 1) * BUFSZ;
        const char* bit = bB + (size_t)it * 32768;

#pragma unroll
        for (int ks = 0; ks < 2; ++ks) {
            half8 b1f[2], b2f[2], a1[2], a2[2];
#pragma unroll
            for (int c = 0; c < 2; c++) {
                b1f[c] = *(const half8*)(bit + ks * 16384 + c * 2048);
                b2f[c] = *(const half8*)(bit + ks * 16384 + c * 2048 + 1024);
            }
#pragma unroll
            for (int r = 0; r < 2; r++) {
                a1[r] = *(const half8*)(cb + ks * 2112 + r * 256 + aroff);
                a2[r] = *(const half8*)(cb + ABUF + ks * 2112 + r * 256 + aroff);
            }
#pragma unroll
            for (int r = 0; r < 2; r++)
#pragma unroll
                for (int c = 0; c < 2; c++) {
                    accm[r][c] = __builtin_amdgcn_mfma_f32_16x16x32_f16(a1[r], b1f[c], accm[r][c], 0, 0, 0);
                    accc[r][c] = __builtin_amdgcn_mfma_f32_16x16x32_f16(a1[r], b2f[c], accc[r][c], 0, 0, 0);
                    accc[r][c] = __builtin_amdgcn_mfma_f32_16x16x32_f16(a2[r], b1f[c], accc[r][c], 0, 0, 0);
                }
        }
        if (it < NITER - 1)
            stage_write(smem + ((it + 1) & 1) * BUFSZ, swoff, n0, n1);
        __syncthreads();
    }

    // write partial logits: part[half][expert][token], expert-major for coalescing
    float* pbase = part + (size_t)half * NTOK * NE;
#pragma unroll
    for (int r = 0; r < 2; r++)
#pragma unroll
        for (int c = 0; c < 2; c++) {
            floatx4 v;
#pragma unroll
            for (int g = 0; g < 4; g++)
                v[g] = accm[r][c][g] + accc[r][c][g] * (1.0f / 2048.0f);
            int e = wave * 32 + c * 16 + lrow;
            int t = tok0 + r * 16 + quad * 4;
            *(floatx4*)(pbase + (size_t)e * NTOK + t) = v;
        }
}

// ---------------- epilogue: sum halves, top-2, softmax, me/ce partials ----------------
__global__ void topk_kernel(const float* __restrict__ part,
                            float* __restrict__ out,
                            float* __restrict__ me_part,
                            float* __restrict__ ce_part) {
    __shared__ float LG[NE * 68];        // [128][68] token-minor, pad to 68
    __shared__ float tmax[ET], tscale[ET];
    __shared__ int hist[NE];
    const int tid = threadIdx.x;
    const int t0  = blockIdx.x * ET;
    const float* p0 = part;
    const float* p1 = part + (size_t)NTOK * NE;

    // load+sum: 4 threads per expert row, 2 passes of 64 experts
    {
        const int q = tid & 3;
#pragma unroll
        for (int pass = 0; pass < 2; pass++) {
            int e = (tid >> 2) + pass * 64;
            const float* r0 = p0 + (size_t)e * NTOK + t0 + q * 16;
            const float* r1 = p1 + (size_t)e * NTOK + t0 + q * 16;
            float* dst = LG + e * 68 + q * 16;
#pragma unroll
            for (int j = 0; j < 16; j += 4) {
                float4 a = *(const float4*)(r0 + j);
                float4 b = *(const float4*)(r1 + j);
                float4 s = {a.x + b.x, a.y + b.y, a.z + b.z, a.w + b.w};
                *(float4*)(dst + j) = s;
            }
        }
    }
    if (tid < NE) hist[tid] = 0;
    __syncthreads();

    if (tid < ET) {
        const int t = tid;
        float m1 = -1e30f, m2 = -1e30f;
        int i1 = 0, i2 = 0;
        for (int e = 0; e < NE; e++) {
            float v = LG[e * 68 + t];
            if (v > m1) { m2 = m1; i2 = i1; m1 = v; i1 = e; }
            else if (v > m2) { m2 = v; i2 = e; }
        }
        float s = 0.f;
        for (int e = 0; e < NE; e++)
            s += __expf((LG[e * 68 + t] - m1) * (1.0f / TEMP));
        tmax[t] = m1;
        tscale[t] = 1.0f / s;
        atomicAdd(&hist[i1], 1);

        const int tg = t0 + t;
        out[tg * 2 + 0] = (float)i1;
        out[tg * 2 + 1] = (float)i2;
        float d = __expf(m2 - m1);
        float g1 = 1.0f / (1.0f + d);
        out[2 * NTOK + tg * 2 + 0] = g1;
        out[2 * NTOK + tg * 2 + 1] = d * g1;
    }
    __syncthreads();

    if (tid < NE) {
        const int e = tid;
        float s = 0.f;
        for (int t = 0; t < ET; t++)
            s += __expf((LG[e * 68 + t] - tmax[t]) * (1.0f / TEMP)) * tscale[t];
        me_part[blockIdx.x * NE + e] = s;
        ce_part[blockIdx.x * NE + e] = (float)hist[e];
    }
}

// ---------------- finalize: reduce partials, loss ----------------
__global__ void finalize_kernel(const float* __restrict__ mp, const float* __restrict__ cp,
                                float* __restrict__ out) {
    __shared__ float red[2 * 8 * 128];
    __shared__ float wsum[2];
    const int tid = threadIdx.x;        // 1024
    const int e = tid & 127, seg = tid >> 7;
    float sm = 0.f, sc = 0.f;
    for (int b = seg; b < NBLK_EPI; b += 8) {
        sm += mp[b * NE + e];
        sc += cp[b * NE + e];
    }
    red[seg * 128 + e] = sm;
    red[1024 + seg * 128 + e] = sc;
    __syncthreads();
    if (tid < 128) {
        float me = 0.f, ce = 0.f;
#pragma unroll
        for (int s = 0; s < 8; s++) {
            me += red[s * 128 + tid];
            ce += red[1024 + s * 128 + tid];
        }
        ce *= (float)NE / (float)NTOK;
        float v = me * ce;
#pragma unroll
        for (int off = 32; off; off >>= 1) v += __shfl_down(v, off);
        if ((tid & 63) == 0) wsum[tid >> 6] = v;
    }
    __syncthreads();
    if (tid == 0) out[4 * NTOK] = (wsum[0] + wsum[1]) / (float)NTOK;
}

extern "C" void kernel_launch(void* const* d_in, const int* in_sizes, int n_in,
                              void* d_out, int out_size, void* d_ws, size_t ws_size,
                              hipStream_t stream) {
    (void)in_sizes; (void)n_in; (void)out_size; (void)ws_size;
    const float* inp = (const float*)d_in[0];
    const float* wg  = (const float*)d_in[1];
    float* out = (float*)d_out;

    _Float16* Bp = (_Float16*)d_ws;                              // 2 MB packed B
    float* part = (float*)((char*)d_ws + (2u << 20));            // 16 MB partial logits
    float* mp = (float*)((char*)d_ws + (18u << 20));             // 128 KB
    float* cp = mp + NBLK_EPI * NE;                              // 128 KB

    pack_b_kernel<<<256, 256, 0, stream>>>(wg, Bp);
    moe_gemm_kernel<<<NBLK_MAIN, 256, 0, stream>>>(inp, Bp, part);
    topk_kernel<<<NBLK_EPI, 256, 0, stream>>>(part, out, mp, cp);
    finalize_kernel<<<1, 1024, 0, stream>>>(mp, cp, out);
}